// Round 2
// baseline (469.702 us; speedup 1.0000x reference)
//
#include <hip/hip_runtime.h>

#define NNODES 50000
#define NEDGES 800000
#define DIM    128
#define NEG_SLOPE 0.2f

// ---------------- workspace layout (bytes) ----------------
// xw      : float[NNODES*DIM]          @ 0            (25,600,000)
// a_src   : float[NNODES]              @ OFF_ASRC
// a_dst   : float[NNODES]              @ OFF_ADST
// counts  : int[NNODES]                @ OFF_CNT
// offsets : int[NNODES+1]              @ OFF_OFFS
// cursor  : int[NNODES]                @ OFF_CUR
// csr_src : int[NEDGES+NNODES]         @ OFF_CSR
// total ≈ 30.0 MB
#define OFF_XW    0
#define OFF_ASRC  (OFF_XW   + (size_t)NNODES*DIM*4)
#define OFF_ADST  (OFF_ASRC + (size_t)NNODES*4)
#define OFF_CNT   (OFF_ADST + (size_t)NNODES*4)
#define OFF_OFFS  (OFF_CNT  + (size_t)NNODES*4)
#define OFF_CUR   (OFF_OFFS + (size_t)(NNODES+16)*4)
#define OFF_CSR   (OFF_CUR  + (size_t)NNODES*4)

// K1: xw = x @ W  (W is [DIN,DOUT] row-major). One wave handles 4 nodes,
// each lane owns 2 output cols (float2). Fused epilogue computes
// a_src[n] = xw[n,:]·att_src and a_dst[n] = xw[n,:]·att_dst via shuffle reduce.
__global__ __launch_bounds__(256) void k_gemm(
    const float* __restrict__ x, const float* __restrict__ W,
    const float* __restrict__ att_src, const float* __restrict__ att_dst,
    float* __restrict__ xw, float* __restrict__ a_src, float* __restrict__ a_dst)
{
    const int lane = threadIdx.x & 63;
    const int wv   = threadIdx.x >> 6;
    const int nb   = blockIdx.x * 16 + wv * 4;   // 3125 blocks * 16 = 50000 exactly

    const float2* __restrict__ W2 = (const float2*)W;
    const float*  __restrict__ x0 = x + (size_t)nb * DIM;

    float2 acc0 = {0.f,0.f}, acc1 = {0.f,0.f}, acc2 = {0.f,0.f}, acc3 = {0.f,0.f};
#pragma unroll 8
    for (int k = 0; k < DIM; ++k) {
        float2 w = W2[k * 64 + lane];
        float x0v = x0[k];
        float x1v = x0[DIM + k];
        float x2v = x0[2*DIM + k];
        float x3v = x0[3*DIM + k];
        acc0.x += x0v * w.x; acc0.y += x0v * w.y;
        acc1.x += x1v * w.x; acc1.y += x1v * w.y;
        acc2.x += x2v * w.x; acc2.y += x2v * w.y;
        acc3.x += x3v * w.x; acc3.y += x3v * w.y;
    }
    float2* __restrict__ xw2 = (float2*)xw;
    xw2[(size_t)(nb+0)*64 + lane] = acc0;
    xw2[(size_t)(nb+1)*64 + lane] = acc1;
    xw2[(size_t)(nb+2)*64 + lane] = acc2;
    xw2[(size_t)(nb+3)*64 + lane] = acc3;

    // fused logits
    float2 as = ((const float2*)att_src)[lane];
    float2 ad = ((const float2*)att_dst)[lane];
    float2 accs[4] = {acc0, acc1, acc2, acc3};
#pragma unroll
    for (int i = 0; i < 4; ++i) {
        float ps = accs[i].x * as.x + accs[i].y * as.y;
        float pd = accs[i].x * ad.x + accs[i].y * ad.y;
#pragma unroll
        for (int off = 32; off; off >>= 1) {
            ps += __shfl_down(ps, off);
            pd += __shfl_down(pd, off);
        }
        if (lane == 0) { a_src[nb+i] = ps; a_dst[nb+i] = pd; }
    }
}

// K2: counts[n] = 1 (self loop)
__global__ void k_init(int* __restrict__ counts) {
    int n = blockIdx.x * blockDim.x + threadIdx.x;
    if (n < NNODES) counts[n] = 1;
}

// K3: degree histogram over dst (edge_index delivered as int32 by harness)
__global__ void k_hist(const int* __restrict__ ei, int* __restrict__ counts) {
    int e = blockIdx.x * blockDim.x + threadIdx.x;
    if (e < NEDGES) {
        int dst = ei[NEDGES + e];
        atomicAdd(&counts[dst], 1);
    }
}

// K4: single-block exclusive scan -> offsets, cursor
__global__ __launch_bounds__(1024) void k_scan(
    const int* __restrict__ counts, int* __restrict__ offsets, int* __restrict__ cursor)
{
    __shared__ int sbuf[2][1024];
    const int t = threadIdx.x;
    const int CH = (NNODES + 1023) / 1024;  // 49
    int lo = t * CH;
    int hi = lo + CH; if (hi > NNODES) hi = NNODES;
    if (lo > NNODES) lo = NNODES;

    int s = 0;
    for (int i = lo; i < hi; ++i) s += counts[i];
    sbuf[0][t] = s;
    __syncthreads();

    int cur = 0, nxt = 1;
    for (int off = 1; off < 1024; off <<= 1) {
        int v = sbuf[cur][t];
        if (t >= off) v += sbuf[cur][t - off];
        sbuf[nxt][t] = v;
        __syncthreads();
        cur ^= 1; nxt ^= 1;
    }
    int incl = sbuf[cur][t];
    int run = incl - s;  // exclusive base
    for (int i = lo; i < hi; ++i) {
        offsets[i] = run;
        cursor[i]  = run;
        run += counts[i];
    }
    if (t == 1023) offsets[NNODES] = sbuf[cur][1023];
}

// K5: scatter edges (+ self loops) into CSR order by dst
__global__ void k_scatter(const int* __restrict__ ei,
                          int* __restrict__ cursor, int* __restrict__ csr)
{
    int i = blockIdx.x * blockDim.x + threadIdx.x;
    if (i < NEDGES + NNODES) {
        int src, dst;
        if (i < NEDGES) { src = ei[i]; dst = ei[NEDGES + i]; }
        else            { src = dst = i - NEDGES; }
        int pos = atomicAdd(&cursor[dst], 1);
        csr[pos] = src;
    }
}

// K6: per-destination online-softmax aggregation. One wave per node;
// lane owns 2 cols (float2). Single coalesced write per node.
__global__ __launch_bounds__(256) void k_agg(
    const float* __restrict__ xw, const float* __restrict__ a_src,
    const float* __restrict__ a_dst, const int* __restrict__ offsets,
    const int* __restrict__ csr, const float* __restrict__ bias,
    float* __restrict__ out)
{
    const int lane = threadIdx.x & 63;
    const int n    = blockIdx.x * 4 + (threadIdx.x >> 6);  // 12500*4 = 50000

    const int beg = offsets[n];
    const int end = offsets[n + 1];
    const float adn = a_dst[n];
    const float2* __restrict__ xw2 = (const float2*)xw;

    float m = -1e30f, l = 0.f;
    float2 acc = {0.f, 0.f};
    for (int j = beg; j < end; ++j) {
        int s = csr[j];
        float e = a_src[s] + adn;
        e = e > 0.f ? e : NEG_SLOPE * e;
        float mn = fmaxf(m, e);
        float scale = __expf(m - mn);   // first iter: exp(-huge) -> 0
        float w     = __expf(e - mn);
        l = l * scale + w;
        float2 v = xw2[(size_t)s * 64 + lane];
        acc.x = acc.x * scale + w * v.x;
        acc.y = acc.y * scale + w * v.y;
        m = mn;
    }
    float2 b = ((const float2*)bias)[lane];
    float ox = acc.x / l + b.x;
    float oy = acc.y / l + b.y;
    ox = ox > 0.f ? ox : (__expf(ox) - 1.f);  // ELU, alpha=1
    oy = oy > 0.f ? oy : (__expf(oy) - 1.f);
    float2 r = {ox, oy};
    ((float2*)out)[(size_t)n * 64 + lane] = r;
}

extern "C" void kernel_launch(void* const* d_in, const int* in_sizes, int n_in,
                              void* d_out, int out_size, void* d_ws, size_t ws_size,
                              hipStream_t stream)
{
    const float* x       = (const float*)d_in[0];
    const int*   ei      = (const int*)d_in[1];    // int32 per harness contract
    const float* W       = (const float*)d_in[2];
    const float* att_src = (const float*)d_in[3];
    const float* att_dst = (const float*)d_in[4];
    const float* bias    = (const float*)d_in[5];
    float*       out     = (float*)d_out;

    char* ws = (char*)d_ws;
    float* xw     = (float*)(ws + OFF_XW);
    float* a_src  = (float*)(ws + OFF_ASRC);
    float* a_dst  = (float*)(ws + OFF_ADST);
    int*   counts = (int*)  (ws + OFF_CNT);
    int*   offs   = (int*)  (ws + OFF_OFFS);
    int*   cursor = (int*)  (ws + OFF_CUR);
    int*   csr    = (int*)  (ws + OFF_CSR);

    k_gemm<<<3125, 256, 0, stream>>>(x, W, att_src, att_dst, xw, a_src, a_dst);
    k_init<<<(NNODES + 255) / 256, 256, 0, stream>>>(counts);
    k_hist<<<(NEDGES + 255) / 256, 256, 0, stream>>>(ei, counts);
    k_scan<<<1, 1024, 0, stream>>>(counts, offs, cursor);
    k_scatter<<<(NEDGES + NNODES + 255) / 256, 256, 0, stream>>>(ei, cursor, csr);
    k_agg<<<NNODES / 4, 256, 0, stream>>>(xw, a_src, a_dst, offs, csr, bias, out);
}

// Round 3
// 298.202 us; speedup vs baseline: 1.5751x; 1.5751x over previous
//
#include <hip/hip_runtime.h>

#define NNODES 50000
#define NEDGES 800000
#define DIM    128
#define NEG_SLOPE 0.2f

#define NPB     40     // nodes per block in k_gemm (1250 blocks * 40 = 50000)
#define NPW     10     // nodes per wave (4 waves/block)
#define SCAN_B  196    // ceil(50000/256)

// ---------------- workspace layout (bytes) ----------------
#define OFF_XW    0
#define OFF_ASRC  (OFF_XW   + (size_t)NNODES*DIM*4)
#define OFF_ADST  (OFF_ASRC + (size_t)NNODES*4)
#define OFF_CNT   (OFF_ADST + (size_t)NNODES*4)
#define OFF_OFFS  (OFF_CNT  + (size_t)NNODES*4)
#define OFF_CUR   (OFF_OFFS + (size_t)(NNODES+16)*4)
#define OFF_CSR   (OFF_CUR  + (size_t)NNODES*4)
#define OFF_BS    (OFF_CSR  + (size_t)(NEDGES+NNODES)*4)
#define OFF_BB    (OFF_BS   + (size_t)256*4)

// K1: xw = x @ W with LDS-staged x. Block: 256 thr, 40 nodes.
// Wave handles 10 nodes; lane owns output cols {2*lane, 2*lane+1}.
// Fused epilogue: a_src/a_dst logits via shuffle reduction.
__global__ __launch_bounds__(256) void k_gemm(
    const float* __restrict__ x, const float* __restrict__ W,
    const float* __restrict__ att_src, const float* __restrict__ att_dst,
    float* __restrict__ xw, float* __restrict__ a_src, float* __restrict__ a_dst)
{
    __shared__ float4 sx4[NPB * DIM / 4];          // 20 KB
    const int t    = threadIdx.x;
    const int lane = t & 63;
    const int wv   = t >> 6;
    const int base = blockIdx.x * NPB;

    // stage x[base .. base+40) rows: 5120 floats = 1280 float4, 5 per thread
    const float4* __restrict__ xg4 = (const float4*)x + (size_t)base * (DIM / 4);
#pragma unroll
    for (int j = 0; j < 5; ++j)
        sx4[t + 256 * j] = xg4[t + 256 * j];
    __syncthreads();

    const float2* __restrict__ W2 = (const float2*)W;

    float2 acc[NPW];
#pragma unroll
    for (int n = 0; n < NPW; ++n) acc[n] = make_float2(0.f, 0.f);

    for (int k = 0; k < DIM; k += 4) {
        float2 w0 = W2[(k + 0) * 64 + lane];
        float2 w1 = W2[(k + 1) * 64 + lane];
        float2 w2 = W2[(k + 2) * 64 + lane];
        float2 w3 = W2[(k + 3) * 64 + lane];
#pragma unroll
        for (int n = 0; n < NPW; ++n) {
            float4 xv = sx4[(wv * NPW + n) * (DIM / 4) + (k >> 2)];
            acc[n].x += xv.x * w0.x; acc[n].y += xv.x * w0.y;
            acc[n].x += xv.y * w1.x; acc[n].y += xv.y * w1.y;
            acc[n].x += xv.z * w2.x; acc[n].y += xv.z * w2.y;
            acc[n].x += xv.w * w3.x; acc[n].y += xv.w * w3.y;
        }
    }

    float2* __restrict__ xw2 = (float2*)xw;
    float2 as = ((const float2*)att_src)[lane];
    float2 ad = ((const float2*)att_dst)[lane];
#pragma unroll
    for (int n = 0; n < NPW; ++n) {
        const int node = base + wv * NPW + n;
        xw2[(size_t)node * 64 + lane] = acc[n];
        float ps = acc[n].x * as.x + acc[n].y * as.y;
        float pd = acc[n].x * ad.x + acc[n].y * ad.y;
#pragma unroll
        for (int off = 32; off; off >>= 1) {
            ps += __shfl_down(ps, off);
            pd += __shfl_down(pd, off);
        }
        if (lane == 0) { a_src[node] = ps; a_dst[node] = pd; }
    }
}

// K2: counts[n] = 1 (self loop)
__global__ void k_init(int* __restrict__ counts) {
    int n = blockIdx.x * blockDim.x + threadIdx.x;
    if (n < NNODES) counts[n] = 1;
}

// K3: degree histogram over dst (edge_index delivered as int32)
__global__ void k_hist(const int* __restrict__ ei, int* __restrict__ counts) {
    int e = blockIdx.x * blockDim.x + threadIdx.x;
    if (e < NEDGES) {
        int dst = ei[NEDGES + e];
        atomicAdd(&counts[dst], 1);
    }
}

// K4a: per-block reduction of counts -> blockSums[196]
__global__ __launch_bounds__(256) void k_scan1(
    const int* __restrict__ counts, int* __restrict__ blockSums)
{
    const int t = threadIdx.x;
    const int i = blockIdx.x * 256 + t;
    int v = (i < NNODES) ? counts[i] : 0;
#pragma unroll
    for (int off = 32; off; off >>= 1) v += __shfl_down(v, off);
    __shared__ int ws[4];
    if ((t & 63) == 0) ws[t >> 6] = v;
    __syncthreads();
    if (t == 0) blockSums[blockIdx.x] = ws[0] + ws[1] + ws[2] + ws[3];
}

// K4b: single-block exclusive scan of 196 block sums -> blockBase; total -> offsets[N]
__global__ __launch_bounds__(256) void k_scan2(
    const int* __restrict__ blockSums, int* __restrict__ blockBase,
    int* __restrict__ offsets)
{
    const int t = threadIdx.x;
    __shared__ int sb[2][256];
    int v = (t < SCAN_B) ? blockSums[t] : 0;
    int cur = 0;
    sb[0][t] = v;
    __syncthreads();
    for (int off = 1; off < 256; off <<= 1) {
        int nv = sb[cur][t] + (t >= off ? sb[cur][t - off] : 0);
        __syncthreads();
        sb[cur ^ 1][t] = nv;
        __syncthreads();
        cur ^= 1;
    }
    int incl = sb[cur][t];
    if (t < SCAN_B) blockBase[t] = incl - v;
    if (t == SCAN_B - 1) offsets[NNODES] = incl;
}

// K4c: intra-block exclusive scan + base -> offsets, cursor
__global__ __launch_bounds__(256) void k_scan3(
    const int* __restrict__ counts, const int* __restrict__ blockBase,
    int* __restrict__ offsets, int* __restrict__ cursor)
{
    const int t = threadIdx.x;
    const int i = blockIdx.x * 256 + t;
    int v = (i < NNODES) ? counts[i] : 0;
    __shared__ int sb[2][256];
    int cur = 0;
    sb[0][t] = v;
    __syncthreads();
    for (int off = 1; off < 256; off <<= 1) {
        int nv = sb[cur][t] + (t >= off ? sb[cur][t - off] : 0);
        __syncthreads();
        sb[cur ^ 1][t] = nv;
        __syncthreads();
        cur ^= 1;
    }
    int excl = sb[cur][t] - v;
    if (i < NNODES) {
        int o = blockBase[blockIdx.x] + excl;
        offsets[i] = o;
        cursor[i]  = o;
    }
}

// K5: scatter edges (+ self loops) into CSR order by dst
__global__ void k_scatter(const int* __restrict__ ei,
                          int* __restrict__ cursor, int* __restrict__ csr)
{
    int i = blockIdx.x * blockDim.x + threadIdx.x;
    if (i < NEDGES + NNODES) {
        int src, dst;
        if (i < NEDGES) { src = ei[i]; dst = ei[NEDGES + i]; }
        else            { src = dst = i - NEDGES; }
        int pos = atomicAdd(&cursor[dst], 1);
        csr[pos] = src;
    }
}

// K6: per-destination online-softmax aggregation. One wave per node;
// lane owns 2 cols (float2). Single coalesced write per node.
__global__ __launch_bounds__(256) void k_agg(
    const float* __restrict__ xw, const float* __restrict__ a_src,
    const float* __restrict__ a_dst, const int* __restrict__ offsets,
    const int* __restrict__ csr, const float* __restrict__ bias,
    float* __restrict__ out)
{
    const int lane = threadIdx.x & 63;
    const int n    = blockIdx.x * 4 + (threadIdx.x >> 6);

    const int beg = offsets[n];
    const int end = offsets[n + 1];
    const float adn = a_dst[n];
    const float2* __restrict__ xw2 = (const float2*)xw;

    float m = -1e30f, l = 0.f;
    float2 acc = {0.f, 0.f};
    for (int j = beg; j < end; ++j) {
        int s = csr[j];
        float e = a_src[s] + adn;
        e = e > 0.f ? e : NEG_SLOPE * e;
        float mn = fmaxf(m, e);
        float scale = __expf(m - mn);
        float w     = __expf(e - mn);
        l = l * scale + w;
        float2 v = xw2[(size_t)s * 64 + lane];
        acc.x = acc.x * scale + w * v.x;
        acc.y = acc.y * scale + w * v.y;
        m = mn;
    }
    float2 b = ((const float2*)bias)[lane];
    float ox = acc.x / l + b.x;
    float oy = acc.y / l + b.y;
    ox = ox > 0.f ? ox : (__expf(ox) - 1.f);
    oy = oy > 0.f ? oy : (__expf(oy) - 1.f);
    float2 r = {ox, oy};
    ((float2*)out)[(size_t)n * 64 + lane] = r;
}

extern "C" void kernel_launch(void* const* d_in, const int* in_sizes, int n_in,
                              void* d_out, int out_size, void* d_ws, size_t ws_size,
                              hipStream_t stream)
{
    const float* x       = (const float*)d_in[0];
    const int*   ei      = (const int*)d_in[1];
    const float* W       = (const float*)d_in[2];
    const float* att_src = (const float*)d_in[3];
    const float* att_dst = (const float*)d_in[4];
    const float* bias    = (const float*)d_in[5];
    float*       out     = (float*)d_out;

    char* ws = (char*)d_ws;
    float* xw     = (float*)(ws + OFF_XW);
    float* a_src  = (float*)(ws + OFF_ASRC);
    float* a_dst  = (float*)(ws + OFF_ADST);
    int*   counts = (int*)  (ws + OFF_CNT);
    int*   offs   = (int*)  (ws + OFF_OFFS);
    int*   cursor = (int*)  (ws + OFF_CUR);
    int*   csr    = (int*)  (ws + OFF_CSR);
    int*   bsums  = (int*)  (ws + OFF_BS);
    int*   bbase  = (int*)  (ws + OFF_BB);

    k_gemm<<<NNODES / NPB, 256, 0, stream>>>(x, W, att_src, att_dst, xw, a_src, a_dst);
    k_init<<<(NNODES + 255) / 256, 256, 0, stream>>>(counts);
    k_hist<<<(NEDGES + 255) / 256, 256, 0, stream>>>(ei, counts);
    k_scan1<<<SCAN_B, 256, 0, stream>>>(counts, bsums);
    k_scan2<<<1, 256, 0, stream>>>(bsums, bbase, offs);
    k_scan3<<<SCAN_B, 256, 0, stream>>>(counts, bbase, offs, cursor);
    k_scatter<<<(NEDGES + NNODES + 255) / 256, 256, 0, stream>>>(ei, cursor, csr);
    k_agg<<<NNODES / 4, 256, 0, stream>>>(xw, a_src, a_dst, offs, csr, bias, out);
}

// Round 4
// 279.973 us; speedup vs baseline: 1.6777x; 1.0651x over previous
//
#include <hip/hip_runtime.h>
#include <hip/hip_bf16.h>

#define NNODES 50000
#define NEDGES 800000
#define DIM    128
#define NEG_SLOPE 0.2f

#define NPB     40     // nodes per block in k_gemm (1250 blocks * 40 = 50000)
#define NPW     10     // nodes per wave (4 waves/block)
#define SCAN_B  196    // ceil(50000/256)

// ---------------- workspace layout (bytes) ----------------
// xw is stored ONLY as bf16 (gather payload); logits are fp32 from the GEMM epilogue.
#define OFF_XW    0
#define OFF_ASRC  (OFF_XW   + (size_t)NNODES*DIM*2)
#define OFF_ADST  (OFF_ASRC + (size_t)NNODES*4)
#define OFF_CNT   (OFF_ADST + (size_t)NNODES*4)
#define OFF_OFFS  (OFF_CNT  + (size_t)NNODES*4)
#define OFF_CUR   (OFF_OFFS + (size_t)(NNODES+16)*4)
#define OFF_CSR   (OFF_CUR  + (size_t)NNODES*4)
#define OFF_BS    (OFF_CSR  + (size_t)(NEDGES+NNODES)*4)
#define OFF_BB    (OFF_BS   + (size_t)256*4)

// K1: xw = x @ W with LDS-staged x. Block: 256 thr, 40 nodes.
// Wave handles 10 nodes; lane owns output cols {2*lane, 2*lane+1}.
// Fused epilogue: a_src/a_dst logits (fp32) + bf16x2 packed xw store.
__global__ __launch_bounds__(256) void k_gemm(
    const float* __restrict__ x, const float* __restrict__ W,
    const float* __restrict__ att_src, const float* __restrict__ att_dst,
    __hip_bfloat162* __restrict__ xwh, float* __restrict__ a_src, float* __restrict__ a_dst)
{
    __shared__ float4 sx4[NPB * DIM / 4];          // 20 KB
    const int t    = threadIdx.x;
    const int lane = t & 63;
    const int wv   = t >> 6;
    const int base = blockIdx.x * NPB;

    const float4* __restrict__ xg4 = (const float4*)x + (size_t)base * (DIM / 4);
#pragma unroll
    for (int j = 0; j < 5; ++j)
        sx4[t + 256 * j] = xg4[t + 256 * j];
    __syncthreads();

    const float2* __restrict__ W2 = (const float2*)W;

    float2 acc[NPW];
#pragma unroll
    for (int n = 0; n < NPW; ++n) acc[n] = make_float2(0.f, 0.f);

    for (int k = 0; k < DIM; k += 4) {
        float2 w0 = W2[(k + 0) * 64 + lane];
        float2 w1 = W2[(k + 1) * 64 + lane];
        float2 w2 = W2[(k + 2) * 64 + lane];
        float2 w3 = W2[(k + 3) * 64 + lane];
#pragma unroll
        for (int n = 0; n < NPW; ++n) {
            float4 xv = sx4[(wv * NPW + n) * (DIM / 4) + (k >> 2)];
            acc[n].x += xv.x * w0.x; acc[n].y += xv.x * w0.y;
            acc[n].x += xv.y * w1.x; acc[n].y += xv.y * w1.y;
            acc[n].x += xv.z * w2.x; acc[n].y += xv.z * w2.y;
            acc[n].x += xv.w * w3.x; acc[n].y += xv.w * w3.y;
        }
    }

    float2 as = ((const float2*)att_src)[lane];
    float2 ad = ((const float2*)att_dst)[lane];
#pragma unroll
    for (int n = 0; n < NPW; ++n) {
        const int node = base + wv * NPW + n;
        xwh[(size_t)node * 64 + lane] = __float22bfloat162_rn(acc[n]);
        float ps = acc[n].x * as.x + acc[n].y * as.y;
        float pd = acc[n].x * ad.x + acc[n].y * ad.y;
#pragma unroll
        for (int off = 32; off; off >>= 1) {
            ps += __shfl_down(ps, off);
            pd += __shfl_down(pd, off);
        }
        if (lane == 0) { a_src[node] = ps; a_dst[node] = pd; }
    }
}

// K2: counts[n] = 1 (self loop)
__global__ void k_init(int* __restrict__ counts) {
    int n = blockIdx.x * blockDim.x + threadIdx.x;
    if (n < NNODES) counts[n] = 1;
}

// K3: degree histogram over dst (edge_index delivered as int32)
__global__ void k_hist(const int* __restrict__ ei, int* __restrict__ counts) {
    int e = blockIdx.x * blockDim.x + threadIdx.x;
    if (e < NEDGES) {
        int dst = ei[NEDGES + e];
        atomicAdd(&counts[dst], 1);
    }
}

// K4a: per-block reduction of counts -> blockSums[196]
__global__ __launch_bounds__(256) void k_scan1(
    const int* __restrict__ counts, int* __restrict__ blockSums)
{
    const int t = threadIdx.x;
    const int i = blockIdx.x * 256 + t;
    int v = (i < NNODES) ? counts[i] : 0;
#pragma unroll
    for (int off = 32; off; off >>= 1) v += __shfl_down(v, off);
    __shared__ int ws[4];
    if ((t & 63) == 0) ws[t >> 6] = v;
    __syncthreads();
    if (t == 0) blockSums[blockIdx.x] = ws[0] + ws[1] + ws[2] + ws[3];
}

// K4b: single-block exclusive scan of 196 block sums -> blockBase; total -> offsets[N]
__global__ __launch_bounds__(256) void k_scan2(
    const int* __restrict__ blockSums, int* __restrict__ blockBase,
    int* __restrict__ offsets)
{
    const int t = threadIdx.x;
    __shared__ int sb[2][256];
    int v = (t < SCAN_B) ? blockSums[t] : 0;
    int cur = 0;
    sb[0][t] = v;
    __syncthreads();
    for (int off = 1; off < 256; off <<= 1) {
        int nv = sb[cur][t] + (t >= off ? sb[cur][t - off] : 0);
        __syncthreads();
        sb[cur ^ 1][t] = nv;
        __syncthreads();
        cur ^= 1;
    }
    int incl = sb[cur][t];
    if (t < SCAN_B) blockBase[t] = incl - v;
    if (t == SCAN_B - 1) offsets[NNODES] = incl;
}

// K4c: intra-block exclusive scan + base -> offsets, cursor
__global__ __launch_bounds__(256) void k_scan3(
    const int* __restrict__ counts, const int* __restrict__ blockBase,
    int* __restrict__ offsets, int* __restrict__ cursor)
{
    const int t = threadIdx.x;
    const int i = blockIdx.x * 256 + t;
    int v = (i < NNODES) ? counts[i] : 0;
    __shared__ int sb[2][256];
    int cur = 0;
    sb[0][t] = v;
    __syncthreads();
    for (int off = 1; off < 256; off <<= 1) {
        int nv = sb[cur][t] + (t >= off ? sb[cur][t - off] : 0);
        __syncthreads();
        sb[cur ^ 1][t] = nv;
        __syncthreads();
        cur ^= 1;
    }
    int excl = sb[cur][t] - v;
    if (i < NNODES) {
        int o = blockBase[blockIdx.x] + excl;
        offsets[i] = o;
        cursor[i]  = o;
    }
}

// K5: scatter edges (+ self loops) into CSR order by dst
__global__ void k_scatter(const int* __restrict__ ei,
                          int* __restrict__ cursor, int* __restrict__ csr)
{
    int i = blockIdx.x * blockDim.x + threadIdx.x;
    if (i < NEDGES + NNODES) {
        int src, dst;
        if (i < NEDGES) { src = ei[i]; dst = ei[NEDGES + i]; }
        else            { src = dst = i - NEDGES; }
        int pos = atomicAdd(&cursor[dst], 1);
        csr[pos] = src;
    }
}

// K6: per-destination online-softmax aggregation over bf16 xw.
// One wave per node; lane owns 2 cols (one bf16x2 = 4B/lane -> 256B/row).
// One-iteration software prefetch breaks the csr->payload dependence chain.
__global__ __launch_bounds__(256) void k_agg(
    const __hip_bfloat162* __restrict__ xwh, const float* __restrict__ a_src,
    const float* __restrict__ a_dst, const int* __restrict__ offsets,
    const int* __restrict__ csr, const float* __restrict__ bias,
    float* __restrict__ out)
{
    const int lane = threadIdx.x & 63;
    const int n    = blockIdx.x * 4 + (threadIdx.x >> 6);

    const int beg = offsets[n];
    const int end = offsets[n + 1];
    const float adn = a_dst[n];

    // prefetch iteration 0 (degree >= 1 always: self loop)
    int s = csr[beg];
    float asv = a_src[s];
    __hip_bfloat162 v = xwh[(size_t)s * 64 + lane];

    float m = -1e30f, l = 0.f;
    float2 acc = {0.f, 0.f};
    for (int j = beg; j < end; ++j) {
        // issue next iteration's loads before the dependent math
        int s1 = 0;
        if (j + 1 < end) s1 = csr[j + 1];
        float asv1 = a_src[s1];
        __hip_bfloat162 v1 = xwh[(size_t)s1 * 64 + lane];

        float e = asv + adn;
        e = e > 0.f ? e : NEG_SLOPE * e;
        float mn = fmaxf(m, e);
        float scale = __expf(m - mn);
        float w     = __expf(e - mn);
        l = l * scale + w;
        float2 vf = __bfloat1622float2(v);
        acc.x = acc.x * scale + w * vf.x;
        acc.y = acc.y * scale + w * vf.y;
        m = mn;

        asv = asv1; v = v1;
    }
    float2 b = ((const float2*)bias)[lane];
    float ox = acc.x / l + b.x;
    float oy = acc.y / l + b.y;
    ox = ox > 0.f ? ox : (__expf(ox) - 1.f);
    oy = oy > 0.f ? oy : (__expf(oy) - 1.f);
    float2 r = {ox, oy};
    ((float2*)out)[(size_t)n * 64 + lane] = r;
}

extern "C" void kernel_launch(void* const* d_in, const int* in_sizes, int n_in,
                              void* d_out, int out_size, void* d_ws, size_t ws_size,
                              hipStream_t stream)
{
    const float* x       = (const float*)d_in[0];
    const int*   ei      = (const int*)d_in[1];
    const float* W       = (const float*)d_in[2];
    const float* att_src = (const float*)d_in[3];
    const float* att_dst = (const float*)d_in[4];
    const float* bias    = (const float*)d_in[5];
    float*       out     = (float*)d_out;

    char* ws = (char*)d_ws;
    __hip_bfloat162* xwh = (__hip_bfloat162*)(ws + OFF_XW);
    float* a_src  = (float*)(ws + OFF_ASRC);
    float* a_dst  = (float*)(ws + OFF_ADST);
    int*   counts = (int*)  (ws + OFF_CNT);
    int*   offs   = (int*)  (ws + OFF_OFFS);
    int*   cursor = (int*)  (ws + OFF_CUR);
    int*   csr    = (int*)  (ws + OFF_CSR);
    int*   bsums  = (int*)  (ws + OFF_BS);
    int*   bbase  = (int*)  (ws + OFF_BB);

    k_gemm<<<NNODES / NPB, 256, 0, stream>>>(x, W, att_src, att_dst, xwh, a_src, a_dst);
    k_init<<<(NNODES + 255) / 256, 256, 0, stream>>>(counts);
    k_hist<<<(NEDGES + 255) / 256, 256, 0, stream>>>(ei, counts);
    k_scan1<<<SCAN_B, 256, 0, stream>>>(counts, bsums);
    k_scan2<<<1, 256, 0, stream>>>(bsums, bbase, offs);
    k_scan3<<<SCAN_B, 256, 0, stream>>>(counts, bbase, offs, cursor);
    k_scatter<<<(NEDGES + NNODES + 255) / 256, 256, 0, stream>>>(ei, cursor, csr);
    k_agg<<<NNODES / 4, 256, 0, stream>>>(xwh, a_src, a_dst, offs, csr, bias, out);
}